// Round 10
// baseline (84.183 us; speedup 1.0000x reference)
//
#include <hip/hip_runtime.h>

#define L 2048
#define H 8
#define S 128
#define B 8
#define HS 1024

// ============ K1: per-(b,h) direct q-slice + A-GEMV slice; b==0 blocks write E/Z scan ============
// grid (B, H) = 64 blocks x 512 threads.
// qs[s] = (1/Z[L-1,h]) * sum_j exp(W[L-1-j,h]) * x[b,j,s]
// partial_v[(b*H+h)*HS + e] = sum_s qs[s] * A[(h*S+s)*HS + e]
__global__ __launch_bounds__(512) void k1_qv(const float* __restrict__ W,
                                             const float* __restrict__ x,
                                             const float* __restrict__ A,
                                             float* __restrict__ E,
                                             float* __restrict__ Z,
                                             float* __restrict__ partial_v,
                                             unsigned* __restrict__ counters) {
  const int b = blockIdx.x, h = blockIdx.y;
  const int t = threadIdx.x;
  if (b == 0 && h == 0 && t == 0) counters[0] = 0u;   // K4 last-block gate

  __shared__ float ew[L];          // ew[j] = exp(W[L-1-j, h])   (8 KB)
  __shared__ float qpart[16][S];   // j-group partials            (8 KB)
  __shared__ float qs[S];
  __shared__ float red[512];

  // --- build ew + Zlast ---
  float myE[4];
#pragma unroll
  for (int k = 0; k < 4; ++k) {
    const int j = t * 4 + k;
    myE[k] = expf(W[(size_t)(L - 1 - j) * H + h]);
    ew[j] = myE[k];
  }
  red[t] = ((myE[0] + myE[1]) + (myE[2] + myE[3]));
  __syncthreads();
  for (int off = 256; off > 0; off >>= 1) {
    if (t < off) red[t] += red[t + off];
    __syncthreads();
  }
  const float invZ = 1.f / red[0];
  __syncthreads();                 // everyone has read red[0]

  // --- b==0: full E/Z prefix scan for this h (for K3) ---
  if (b == 0) {
    float e4[4];
    float run = 0.f;
#pragma unroll
    for (int k = 0; k < 4; ++k) {
      const int d = t * 4 + k;
      e4[k] = ew[L - 1 - d];       // E[d,h]
      run += e4[k];
    }
    red[t] = run;
    __syncthreads();
    for (int off = 1; off < 512; off <<= 1) {
      float v = (t >= off) ? red[t - off] : 0.f;
      __syncthreads();
      red[t] += v;
      __syncthreads();
    }
    float c = (t == 0) ? 0.f : red[t - 1];
#pragma unroll
    for (int k = 0; k < 4; ++k) {
      const int d = t * 4 + k;
      c += e4[k];
      E[h * L + d] = e4[k];
      Z[h * L + d] = c;
    }
  }

  // --- j-sum: 16 j-groups x 32 float4-lanes ---
  {
    const int s4 = t & 31;
    const int jg = t >> 5;
    const float4* __restrict__ x4 = (const float4*)(x + (size_t)b * L * S);
    float4 acc = make_float4(0.f, 0.f, 0.f, 0.f);
    const int jbase = jg * 128;
#pragma unroll 4
    for (int jj = 0; jj < 128; ++jj) {
      const int j = jbase + jj;
      const float w = ew[j];
      const float4 xv = x4[(size_t)j * 32 + s4];
      acc.x += w * xv.x; acc.y += w * xv.y; acc.z += w * xv.z; acc.w += w * xv.w;
    }
    qpart[jg][s4 * 4 + 0] = acc.x;
    qpart[jg][s4 * 4 + 1] = acc.y;
    qpart[jg][s4 * 4 + 2] = acc.z;
    qpart[jg][s4 * 4 + 3] = acc.w;
  }
  __syncthreads();
  if (t < S) {
    float q = 0.f;
#pragma unroll
    for (int g = 0; g < 16; ++g) q += qpart[g][t];
    qs[t] = q * invZ;
  }
  __syncthreads();

  // --- GEMV slice: e = t and t+512 ---
  {
    const float* __restrict__ Ab = A + (size_t)h * S * HS;
    float acc0 = 0.f, acc1 = 0.f;
#pragma unroll 4
    for (int s = 0; s < S; ++s) {
      const float q = qs[s];                         // LDS broadcast
      acc0 += q * Ab[(size_t)s * HS + t];
      acc1 += q * Ab[(size_t)s * HS + t + 512];
    }
    partial_v[(size_t)(b * H + h) * HS + t] = acc0;
    partial_v[(size_t)(b * H + h) * HS + t + 512] = acc1;
  }
}

// ============ K2: v-reduce + u ============
// grid (B, 16) = 128 blocks x 512 threads; j-chunks of 128.
__global__ __launch_bounds__(512) void k2_u(const float* __restrict__ x,
                                            const float* __restrict__ partial_v,
                                            float* __restrict__ u_pad) {
  const int b = blockIdx.x, jc = blockIdx.y;
  const int t = threadIdx.x;
  __shared__ float vs[HS];            // 4 KB
  __shared__ float up[4][H][128];     // 16 KB
#pragma unroll
  for (int k = 0; k < 2; ++k) {
    const int i = t + k * 512;
    float a = 0.f;
#pragma unroll
    for (int hh = 0; hh < H; ++hh) a += partial_v[(size_t)(b * H + hh) * HS + i];
    vs[i] = a;
  }
  __syncthreads();
  const int jl = t & 127, sq = t >> 7;      // 4-way s split (32 s each)
  const int j = jc * 128 + jl;
  const float4* __restrict__ xr = (const float4*)(x + ((size_t)b * L + j) * S) + sq * 8;
  float4 xv[8];
#pragma unroll
  for (int i = 0; i < 8; ++i) xv[i] = xr[i];
  float acc[H];
#pragma unroll
  for (int hh = 0; hh < H; ++hh) {
    const float4* __restrict__ vv = (const float4*)(vs + hh * S + sq * 32);
    float a = 0.f;
#pragma unroll
    for (int i = 0; i < 8; ++i) {
      const float4 w = vv[i];               // LDS broadcast within 32-lane group
      a += xv[i].x * w.x + xv[i].y * w.y + xv[i].z * w.z + xv[i].w * w.w;
    }
    acc[hh] = a;
  }
#pragma unroll
  for (int hh = 0; hh < H; ++hh) up[sq][hh][jl] = acc[hh];
  __syncthreads();
#pragma unroll
  for (int k = 0; k < 2; ++k) {
    const int idx = t + k * 512;            // [0,1024): h = idx>>7, j2 = idx&127
    const int hh = idx >> 7, j2 = idx & 127;
    const float sv = up[0][hh][j2] + up[1][hh][j2] + up[2][hh][j2] + up[3][hh][j2];
    const size_t rowbase = (size_t)(b * H + hh) * (2 * L);
    u_pad[rowbase + jc * 128 + j2] = 0.f;   // zero pad (front half)
    u_pad[rowbase + L + jc * 128 + j2] = sv;
  }
}

// ============ K3: conv partials, 1088 triangular jobs strip-mined over 256 blocks ============
__global__ __launch_bounds__(256) void k3_conv(const float* __restrict__ u_pad,
                                               const float* __restrict__ E,
                                               const float* __restrict__ Z,
                                               float* __restrict__ partial_s) {
  const int t = threadIdx.x;
  const int tsub = t & 31;
  const int h = t >> 5;
  __shared__ float sred[H][128];
  for (int job = blockIdx.x; job < B * 136; job += 256) {
    const int b = job / 136;
    const int rr = job - b * 136;
    int lt = 0;
    while ((lt + 1) * (lt + 2) / 2 <= rr) ++lt;
    const int dt = rr - lt * (lt + 1) / 2;
    const int l0 = lt * 128;
    const int dbase = dt * 128;
    const int Lb = l0 + tsub * 4;
    const float* __restrict__ ur = u_pad + (size_t)(b * H + h) * (2 * L) + L;
    const float4* __restrict__ Eh4 = (const float4*)(E + h * L);
    float acc0 = 0.f, acc1 = 0.f, acc2 = 0.f, acc3 = 0.f;
    float4 lo = *(const float4*)(ur + Lb - dbase - 4);
    float4 hi = *(const float4*)(ur + Lb - dbase);
#pragma unroll 4
    for (int dd = 0; dd < 128; dd += 4) {
      const int d0 = dbase + dd;
      float4 ev  = Eh4[d0 >> 2];                      // wave-uniform -> scalar load
      float4 nlo = *(const float4*)(ur + Lb - d0 - 8);
      acc0 += ev.x * hi.x; acc1 += ev.x * hi.y; acc2 += ev.x * hi.z; acc3 += ev.x * hi.w;
      acc0 += ev.y * lo.w; acc1 += ev.y * hi.x; acc2 += ev.y * hi.y; acc3 += ev.y * hi.z;
      acc0 += ev.z * lo.z; acc1 += ev.z * lo.w; acc2 += ev.z * hi.x; acc3 += ev.z * hi.y;
      acc0 += ev.w * lo.y; acc1 += ev.w * lo.z; acc2 += ev.w * lo.w; acc3 += ev.w * hi.x;
      hi = lo; lo = nlo;
    }
    const float4 zv = *(const float4*)&Z[h * L + Lb];
    sred[h][tsub * 4 + 0] = acc0 / zv.x;
    sred[h][tsub * 4 + 1] = acc1 / zv.y;
    sred[h][tsub * 4 + 2] = acc2 / zv.z;
    sred[h][tsub * 4 + 3] = acc3 / zv.w;
    __syncthreads();
    if (t < 128) {
      float sc = 0.f;
#pragma unroll
      for (int hh = 0; hh < H; ++hh) sc += sred[hh][t];
      partial_s[((size_t)b * 16 + dt) * L + l0 + t] = sc;
    }
    __syncthreads();   // protect sred before next job
  }
}

// ============ K4: redundant softmax + weighted-sum chunk + last-block final reduce ============
// grid (B, 16) = 128 blocks x 512 threads; l-chunks of 128.
__global__ __launch_bounds__(512) void k4_out(const float* __restrict__ x,
                                              const float* __restrict__ partial_s,
                                              float* __restrict__ partial,
                                              unsigned* __restrict__ counters,
                                              float* __restrict__ out) {
  const int b = blockIdx.x, c = blockIdx.y;
  const int t = threadIdx.x;
  __shared__ float ep[L];          // normalized weights (8 KB)
  __shared__ float red[512];
  __shared__ float part[16][S];    // 8 KB

  // --- Phase A: softmax over scores (thread t owns l in [4t, 4t+4)) ---
  const int l0 = t * 4;
  const int ltmax = t >> 5;                 // (4t)>>7
  float sc[4] = {0.f, 0.f, 0.f, 0.f};
  for (int dt = 0; dt <= ltmax; ++dt) {
    const float4 a = *(const float4*)(partial_s + ((size_t)b * 16 + dt) * L + l0);
    sc[0] += a.x; sc[1] += a.y; sc[2] += a.z; sc[3] += a.w;
  }
  if (t == 511) sc[3] = -3.4e38f;           // l = 2047 excluded
  float mx = fmaxf(fmaxf(sc[0], sc[1]), fmaxf(sc[2], sc[3]));
  red[t] = mx;
  __syncthreads();
  for (int off = 256; off > 0; off >>= 1) {
    if (t < off) red[t] = fmaxf(red[t], red[t + off]);
    __syncthreads();
  }
  mx = red[0];
  __syncthreads();
  float e[4];
  float sm = 0.f;
#pragma unroll
  for (int k = 0; k < 4; ++k) {
    e[k] = (l0 + k < L - 1) ? expf(sc[k] - mx) : 0.f;
    sm += e[k];
  }
  red[t] = sm;
  __syncthreads();
  for (int off = 256; off > 0; off >>= 1) {
    if (t < off) red[t] += red[t + off];
    __syncthreads();
  }
  const float inv = 1.f / red[0];
#pragma unroll
  for (int k = 0; k < 4; ++k) ep[l0 + k] = e[k] * inv;
  __syncthreads();

  // --- Phase B: partial[b,c,s] = sum_{l in 128-chunk c} ep[l] * x[b,l,s] ---
  const int s4 = t & 31;
  const int r = t >> 5;                     // 16 row-groups of 8 l
  const int base = c * 128;
  const float4* __restrict__ x4 = (const float4*)(x + (size_t)b * L * S);
  float4 acc = make_float4(0.f, 0.f, 0.f, 0.f);
#pragma unroll
  for (int k = 0; k < 8; ++k) {
    const int l = base + k * 16 + r;
    const float w = ep[l];
    const float4 xv = x4[(size_t)l * 32 + s4];
    acc.x += w * xv.x; acc.y += w * xv.y; acc.z += w * xv.z; acc.w += w * xv.w;
  }
  part[r][s4 * 4 + 0] = acc.x;
  part[r][s4 * 4 + 1] = acc.y;
  part[r][s4 * 4 + 2] = acc.z;
  part[r][s4 * 4 + 3] = acc.w;
  __syncthreads();
  if (t < S) {
    float smv = 0.f;
#pragma unroll
    for (int rr = 0; rr < 16; ++rr) smv += part[rr][t];
    partial[((size_t)b * 16 + c) * S + t] = smv;
  }
  // --- last-block gate (one-shot, 128 blocks) ---
  __threadfence();
  __syncthreads();
  __shared__ unsigned lastFlag;
  if (t == 0)
    lastFlag = (atomicAdd(&counters[0], 1u) == (unsigned)(B * 16 - 1)) ? 1u : 0u;
  __syncthreads();
  if (lastFlag) {
#pragma unroll
    for (int k = 0; k < 2; ++k) {
      const int idx = t + k * 512;          // b2 = idx>>7, s = idx&127
      const int b2 = idx >> 7, s = idx & 127;
      float a = 0.f;
#pragma unroll 4
      for (int cc = 0; cc < 16; ++cc) a += partial[((size_t)b2 * 16 + cc) * S + s];
      out[b2 * S + s] = a;
    }
  }
}

extern "C" void kernel_launch(void* const* d_in, const int* in_sizes, int n_in,
                              void* d_out, int out_size, void* d_ws, size_t ws_size,
                              hipStream_t stream) {
  const float* x = (const float*)d_in[0];   // (B, L, S) f32
  const float* W = (const float*)d_in[1];   // (L, H)   f32
  const float* A = (const float*)d_in[2];   // (HS, HS) f32
  float* out = (float*)d_out;               // (B, S)   f32

  float* ws        = (float*)d_ws;
  float* E         = ws;                               // H*L    = 16384
  float* Z         = E + H * L;                        // 16384
  float* partial_v = Z + H * L;                        // B*H*HS = 65536
  float* u_pad     = partial_v + (size_t)B * H * HS;   // B*H*2L = 262144
  float* partial_s = u_pad + (size_t)B * H * 2 * L;    // B*16*L = 262144
  float* partial   = partial_s + (size_t)B * 16 * L;   // B*16*S = 16384
  unsigned* counters = (unsigned*)(partial + (size_t)B * 16 * S);
  // total ≈ 2.6 MB of d_ws

  k1_qv  <<<dim3(B, H),  512, 0, stream>>>(W, x, A, E, Z, partial_v, counters);
  k2_u   <<<dim3(B, 16), 512, 0, stream>>>(x, partial_v, u_pad);
  k3_conv<<<256,         256, 0, stream>>>(u_pad, E, Z, partial_s);
  k4_out <<<dim3(B, 16), 512, 0, stream>>>(x, partial_s, partial, counters, out);
}

// Round 11
// 58.830 us; speedup vs baseline: 1.4310x; 1.4310x over previous
//
#include <hip/hip_runtime.h>

#define L 2048
#define H 8
#define S 128
#define B 8
#define HS 1024

// ============ KA: fused {E,Z prefix-scan} + partial_q ============
// grid (B, 16) = 128 blocks. j-chunks of 128.
// partial_q[b,jc,h,s] = sum_{j in chunk jc} E[L-1-j,h] * x[b,j,s]
__global__ __launch_bounds__(256) void kA_prep_qpart(const float* __restrict__ W,
                                                     const float* __restrict__ x,
                                                     float* __restrict__ E,
                                                     float* __restrict__ Z,
                                                     float* __restrict__ partial_q,
                                                     unsigned* __restrict__ counters) {
  const int b = blockIdx.x, jc = blockIdx.y;
  const int t = threadIdx.x;
  if (b == 0 && jc == 0 && t == 0) counters[0] = 0u;   // kF last-block gate

  __shared__ float ew[128][H];      // ew[i][h] = E[h, L-1-(base+i)]   (4 KB)
  __shared__ float part[8][H][S];   // [r][h][s]                      (32 KB)
  __shared__ float tot[256];        // scan scratch

  const int base = jc * 128;
  const int dhi = L - 1 - base;
#pragma unroll
  for (int k = 0; k < 4; ++k) {
    const int idx = t + k * 256;    // [0,1024): i = idx>>3, h = idx&7
    const int i = idx >> 3, h = idx & 7;
    ew[i][h] = expf(W[(size_t)(dhi - i) * H + h]);
  }

  // --- full prefix scan for one h (8 blocks only) ---
  if (b == 0 && jc < H) {
    const int h = jc;
    const int d0 = t * 8;
    float e[8];
    float run = 0.f;
#pragma unroll
    for (int k = 0; k < 8; ++k) {
      float v = expf(W[(size_t)(d0 + k) * H + h]);
      e[k] = v; run += v;
    }
    tot[t] = run;
    __syncthreads();
    for (int off = 1; off < 256; off <<= 1) {
      float v = (t >= off) ? tot[t - off] : 0.f;
      __syncthreads();
      tot[t] += v;
      __syncthreads();
    }
    float c = (t == 0) ? 0.f : tot[t - 1];
#pragma unroll
    for (int k = 0; k < 8; ++k) {
      c += e[k];
      E[h * L + d0 + k] = e[k];
      Z[h * L + d0 + k] = c;
    }
  }
  __syncthreads();   // ew ready (and scan done)

  // --- partial_q main loop: 8 row-groups x 16 rows each ---
  const int s4 = t & 31;
  const int r = t >> 5;
  const float4* __restrict__ x4 = (const float4*)(x + (size_t)b * L * S);
  float4 acc[H];
#pragma unroll
  for (int h = 0; h < H; ++h) acc[h] = make_float4(0.f, 0.f, 0.f, 0.f);
#pragma unroll
  for (int k = 0; k < 16; ++k) {
    const int ll = k * 8 + r;
    const int l = base + ll;
    const float4 xv = x4[(size_t)l * 32 + s4];
#pragma unroll
    for (int h = 0; h < H; ++h) {
      const float w = ew[ll][h];
      acc[h].x += w * xv.x; acc[h].y += w * xv.y;
      acc[h].z += w * xv.z; acc[h].w += w * xv.w;
    }
  }
#pragma unroll
  for (int h = 0; h < H; ++h) {
    part[r][h][s4 * 4 + 0] = acc[h].x;
    part[r][h][s4 * 4 + 1] = acc[h].y;
    part[r][h][s4 * 4 + 2] = acc[h].z;
    part[r][h][s4 * 4 + 3] = acc[h].w;
  }
  __syncthreads();
#pragma unroll
  for (int k = 0; k < 4; ++k) {
    const int idx = t + k * 256;           // h*S + s
    const int h = idx >> 7, s = idx & 127;
    float sm = 0.f;
#pragma unroll
    for (int rr = 0; rr < 8; ++rr) sm += part[rr][h][s];
    partial_q[((size_t)b * 16 + jc) * HS + idx] = sm;
  }
}

// ============ KB: all-batch GEMV over one A-chunk ============
// grid (8 ec, 16 dc) = 128 blocks. Block: e in [ec*128,+128), d in [dc*64,+64).
// Threads: el = t&127 (e lane), dg = t>>7 (2 d-groups of 32).
__global__ __launch_bounds__(256) void kB_v(const float* __restrict__ partial_q,
                                            const float* __restrict__ Z,
                                            const float* __restrict__ A,
                                            float* __restrict__ partial_v) {
  const int ebase = blockIdx.x * 128;
  const int dc = blockIdx.y;
  const int dbase = dc * 64;
  const int t = threadIdx.x;
  __shared__ float ql[8][64];          // 2 KB
  __shared__ float p2[2][8][128];      // 8 KB
  const float invZ = 1.f / Z[(dc >> 1) * L + (L - 1)];   // h = dbase>>7 = dc>>1
#pragma unroll
  for (int k = 0; k < 2; ++k) {
    const int o = t + k * 256;          // [0,512): bb = o>>6, dl = o&63
    const int bb = o >> 6, dl = o & 63;
    const float* __restrict__ pq = partial_q + ((size_t)bb * 16) * HS + dbase + dl;
    float a0 = 0.f, a1 = 0.f, a2 = 0.f, a3 = 0.f;
#pragma unroll
    for (int j4 = 0; j4 < 16; j4 += 4) {
      a0 += pq[(size_t)(j4 + 0) * HS];
      a1 += pq[(size_t)(j4 + 1) * HS];
      a2 += pq[(size_t)(j4 + 2) * HS];
      a3 += pq[(size_t)(j4 + 3) * HS];
    }
    ql[bb][dl] = ((a0 + a1) + (a2 + a3)) * invZ;
  }
  __syncthreads();
  const int el = t & 127, dg = t >> 7;
  const int e = ebase + el;
  const float* __restrict__ Ab = A + (size_t)(dbase + dg * 32) * HS + e;
  float acc[8] = {0.f, 0.f, 0.f, 0.f, 0.f, 0.f, 0.f, 0.f};
#pragma unroll 4
  for (int dd = 0; dd < 32; ++dd) {
    const float a = Ab[(size_t)dd * HS];
    const int d = dg * 32 + dd;
    acc[0] += ql[0][d] * a;
    acc[1] += ql[1][d] * a;
    acc[2] += ql[2][d] * a;
    acc[3] += ql[3][d] * a;
    acc[4] += ql[4][d] * a;
    acc[5] += ql[5][d] * a;
    acc[6] += ql[6][d] * a;
    acc[7] += ql[7][d] * a;
  }
#pragma unroll
  for (int bb = 0; bb < 8; ++bb) p2[dg][bb][el] = acc[bb];
  __syncthreads();
#pragma unroll
  for (int k = 0; k < 4; ++k) {
    const int idx = t + k * 256;        // [0,1024): bb = idx>>7, el2 = idx&127
    const int bb = idx >> 7, el2 = idx & 127;
    partial_v[((size_t)bb * 16 + dc) * HS + ebase + el2] = p2[0][bb][el2] + p2[1][bb][el2];
  }
}

// ============ KC: fused v-reduce + u ============
// grid (B, 16) = 128 blocks. j-chunks of 128. jl = t&127, sq = t>>7 (2 s-halves).
__global__ __launch_bounds__(256) void kC_u(const float* __restrict__ x,
                                            const float* __restrict__ partial_v,
                                            float* __restrict__ u_pad) {
  const int b = blockIdx.x, jc = blockIdx.y;
  const int t = threadIdx.x;
  __shared__ float vs[HS];             // 4 KB
  __shared__ float up[2][H][128];      // 8 KB
#pragma unroll
  for (int k = 0; k < 4; ++k) {
    const int i = t + k * 256;
    float a = 0.f;
#pragma unroll
    for (int dcc = 0; dcc < 16; ++dcc) a += partial_v[((size_t)b * 16 + dcc) * HS + i];
    vs[i] = a;
  }
  __syncthreads();
  const int jl = t & 127, sq = t >> 7;
  const int j = jc * 128 + jl;
  const float4* __restrict__ xr = (const float4*)(x + ((size_t)b * L + j) * S) + sq * 16;
  float4 xv[16];
#pragma unroll
  for (int i = 0; i < 16; ++i) xv[i] = xr[i];
  float acc[H];
#pragma unroll
  for (int h = 0; h < H; ++h) {
    const float4* __restrict__ vv = (const float4*)(vs + h * S + sq * 64);
    float a = 0.f;
#pragma unroll
    for (int i = 0; i < 16; ++i) {
      const float4 w = vv[i];   // same addr across 128-lane group -> LDS broadcast
      a += xv[i].x * w.x + xv[i].y * w.y + xv[i].z * w.z + xv[i].w * w.w;
    }
    acc[h] = a;
  }
#pragma unroll
  for (int h = 0; h < H; ++h) up[sq][h][jl] = acc[h];
  __syncthreads();
#pragma unroll
  for (int k = 0; k < 4; ++k) {
    const int idx = t + k * 256;       // [0,1024): h = idx>>7, j2 = idx&127
    const int h = idx >> 7, j2 = idx & 127;
    const float sv = up[0][h][j2] + up[1][h][j2];
    const size_t rowbase = (size_t)(b * H + h) * (2 * L);
    u_pad[rowbase + jc * 128 + j2] = 0.f;        // zero pad (front half)
    u_pad[rowbase + L + jc * 128 + j2] = sv;
  }
}

// ============ KD: conv partials, 256-wide d-tiles, B*72 = 576 blocks ============
// jobs per lt = floor(lt/2)+1 (dtt covers d in [dtt*256, +256); zero-pad makes d>l free).
__global__ __launch_bounds__(256) void kD_conv(const float* __restrict__ u_pad,
                                               const float* __restrict__ E,
                                               const float* __restrict__ Z,
                                               float* __restrict__ partial_s) {
  const int job = blockIdx.x;
  const int b = job / 72;
  const int rr = job - b * 72;
  int lt = 0, c = 0;
  while (c + (lt / 2 + 1) <= rr) { c += lt / 2 + 1; ++lt; }
  const int dtt = rr - c;
  const int l0 = lt * 128;
  const int dbase = dtt * 256;
  const int t = threadIdx.x;
  const int tsub = t & 31;
  const int h = t >> 5;
  const int Lb = l0 + tsub * 4;
  const float* __restrict__ ur = u_pad + (size_t)(b * H + h) * (2 * L) + L;
  const float4* __restrict__ Eh4 = (const float4*)(E + h * L);
  float acc0 = 0.f, acc1 = 0.f, acc2 = 0.f, acc3 = 0.f;
  float4 lo = *(const float4*)(ur + Lb - dbase - 4);
  float4 hi = *(const float4*)(ur + Lb - dbase);
#pragma unroll 4
  for (int dd = 0; dd < 256; dd += 4) {
    const int d0 = dbase + dd;
    float4 ev  = Eh4[d0 >> 2];                        // wave-uniform -> scalar load
    float4 nlo = *(const float4*)(ur + Lb - d0 - 8);  // zero-pad covers all
    acc0 += ev.x * hi.x; acc1 += ev.x * hi.y; acc2 += ev.x * hi.z; acc3 += ev.x * hi.w;
    acc0 += ev.y * lo.w; acc1 += ev.y * hi.x; acc2 += ev.y * hi.y; acc3 += ev.y * hi.z;
    acc0 += ev.z * lo.z; acc1 += ev.z * lo.w; acc2 += ev.z * hi.x; acc3 += ev.z * hi.y;
    acc0 += ev.w * lo.y; acc1 += ev.w * lo.z; acc2 += ev.w * lo.w; acc3 += ev.w * hi.x;
    hi = lo; lo = nlo;
  }
  __shared__ float sred[H][128];
  const float4 zv = *(const float4*)&Z[h * L + Lb];
  sred[h][tsub * 4 + 0] = acc0 / zv.x;
  sred[h][tsub * 4 + 1] = acc1 / zv.y;
  sred[h][tsub * 4 + 2] = acc2 / zv.z;
  sred[h][tsub * 4 + 3] = acc3 / zv.w;
  __syncthreads();
  if (t < 128) {
    float sc = 0.f;
#pragma unroll
    for (int hh = 0; hh < H; ++hh) sc += sred[hh][t];
    partial_s[((size_t)b * 8 + dtt) * L + l0 + t] = sc;
  }
}

// ============ KF: redundant softmax + 128-l weighted-sum chunk + last-block reduce ============
// grid (B, 16) = 128 blocks.
__global__ __launch_bounds__(256) void kF_out(const float* __restrict__ x,
                                              const float* __restrict__ partial_s,
                                              float* __restrict__ partial,
                                              unsigned* __restrict__ counters,
                                              float* __restrict__ out) {
  const int b = blockIdx.x, c = blockIdx.y;
  const int t = threadIdx.x;
  __shared__ float ep[L];          // 8 KB
  __shared__ float red[256];
  __shared__ float part[8][S];     // 4 KB

  // --- Phase A: scores -> softmax weights (thread t owns l in [8t, 8t+8)) ---
  const int l0 = t * 8;
  const int ltq = t >> 5;                // lt>>1 = floor((t>>4)/2)
  float sc[8];
#pragma unroll
  for (int k = 0; k < 8; ++k) sc[k] = 0.f;
  for (int dtt = 0; dtt <= ltq; ++dtt) {
    const float4* __restrict__ ps = (const float4*)(partial_s + ((size_t)b * 8 + dtt) * L + l0);
    const float4 a = ps[0], c4 = ps[1];
    sc[0] += a.x;  sc[1] += a.y;  sc[2] += a.z;  sc[3] += a.w;
    sc[4] += c4.x; sc[5] += c4.y; sc[6] += c4.z; sc[7] += c4.w;
  }
  if (t == 255) sc[7] = -3.4e38f;        // l = 2047 excluded
  float mx = sc[0];
#pragma unroll
  for (int k = 1; k < 8; ++k) mx = fmaxf(mx, sc[k]);
  red[t] = mx;
  __syncthreads();
  for (int off = 128; off > 0; off >>= 1) {
    if (t < off) red[t] = fmaxf(red[t], red[t + off]);
    __syncthreads();
  }
  mx = red[0];
  __syncthreads();
  float e[8];
  float sm = 0.f;
#pragma unroll
  for (int k = 0; k < 8; ++k) {
    e[k] = (l0 + k < L - 1) ? expf(sc[k] - mx) : 0.f;
    sm += e[k];
  }
  red[t] = sm;
  __syncthreads();
  for (int off = 128; off > 0; off >>= 1) {
    if (t < off) red[t] += red[t + off];
    __syncthreads();
  }
  const float inv = 1.f / red[0];
#pragma unroll
  for (int k = 0; k < 8; ++k) ep[l0 + k] = e[k] * inv;
  __syncthreads();

  // --- Phase B: partial[b,c,s] = sum_{l in 128-chunk c} ep[l] * x[b,l,s] ---
  const int s4 = t & 31;
  const int r = t >> 5;
  const int base = c * 128;
  const float4* __restrict__ x4 = (const float4*)(x + (size_t)b * L * S);
  float4 acc = make_float4(0.f, 0.f, 0.f, 0.f);
#pragma unroll
  for (int k = 0; k < 16; ++k) {
    const int l = base + k * 8 + r;
    const float w = ep[l];
    const float4 xv = x4[(size_t)l * 32 + s4];
    acc.x += w * xv.x; acc.y += w * xv.y; acc.z += w * xv.z; acc.w += w * xv.w;
  }
  part[r][s4 * 4 + 0] = acc.x;
  part[r][s4 * 4 + 1] = acc.y;
  part[r][s4 * 4 + 2] = acc.z;
  part[r][s4 * 4 + 3] = acc.w;
  __syncthreads();
  if (t < S) {
    float smv = 0.f;
#pragma unroll
    for (int rr = 0; rr < 8; ++rr) smv += part[rr][t];
    partial[((size_t)b * 16 + c) * S + t] = smv;
  }
  // --- last-block gate (one-shot, 128 blocks) ---
  __threadfence();
  __syncthreads();
  __shared__ unsigned lastFlag;
  if (t == 0)
    lastFlag = (atomicAdd(&counters[0], 1u) == (unsigned)(B * 16 - 1)) ? 1u : 0u;
  __syncthreads();
  if (lastFlag) {
#pragma unroll
    for (int k = 0; k < 4; ++k) {
      const int idx = t + k * 256;          // b2 = idx>>7, s = idx&127
      const int b2 = idx >> 7, s = idx & 127;
      float a = 0.f;
#pragma unroll 4
      for (int cc = 0; cc < 16; ++cc) a += partial[((size_t)b2 * 16 + cc) * S + s];
      out[b2 * S + s] = a;
    }
  }
}

extern "C" void kernel_launch(void* const* d_in, const int* in_sizes, int n_in,
                              void* d_out, int out_size, void* d_ws, size_t ws_size,
                              hipStream_t stream) {
  const float* x = (const float*)d_in[0];   // (B, L, S) f32
  const float* W = (const float*)d_in[1];   // (L, H)   f32
  const float* A = (const float*)d_in[2];   // (HS, HS) f32
  float* out = (float*)d_out;               // (B, S)   f32

  float* ws        = (float*)d_ws;
  float* E         = ws;                               // H*L     = 16384
  float* Z         = E + H * L;                        // 16384
  float* partial_q = Z + H * L;                        // B*16*HS = 131072
  float* partial_v = partial_q + (size_t)B * 16 * HS;  // B*16*HS = 131072
  float* u_pad     = partial_v + (size_t)B * 16 * HS;  // B*H*2L  = 262144
  float* partial_s = u_pad + (size_t)B * H * 2 * L;    // B*8*L   = 131072
  float* partial   = partial_s + (size_t)B * 8 * L;    // B*16*S  = 16384
  unsigned* counters = (unsigned*)(partial + (size_t)B * 16 * S);
  // total ≈ 2.8 MB of d_ws

  kA_prep_qpart<<<dim3(B, 16), 256, 0, stream>>>(W, x, E, Z, partial_q, counters);
  kB_v         <<<dim3(8, 16), 256, 0, stream>>>(partial_q, Z, A, partial_v);
  kC_u         <<<dim3(B, 16), 256, 0, stream>>>(x, partial_v, u_pad);
  kD_conv      <<<B * 72,      256, 0, stream>>>(u_pad, E, Z, partial_s);
  kF_out       <<<dim3(B, 16), 256, 0, stream>>>(x, partial_s, partial, counters, out);
}

// Round 12
// 58.805 us; speedup vs baseline: 1.4316x; 1.0004x over previous
//
#include <hip/hip_runtime.h>

#define L 2048
#define H 8
#define S 128
#define B 8
#define HS 1024

// ============ KA: fused {E,Z prefix-scan} + partial_q ============
// grid (B, 16) = 128 blocks x 512 threads. j-chunks of 128.
// partial_q[b,jc,h,s] = sum_{j in chunk jc} E[L-1-j,h] * x[b,j,s]
__global__ __launch_bounds__(512) void kA_prep_qpart(const float* __restrict__ W,
                                                     const float* __restrict__ x,
                                                     float* __restrict__ E,
                                                     float* __restrict__ Z,
                                                     float* __restrict__ partial_q,
                                                     unsigned* __restrict__ counters) {
  const int b = blockIdx.x, jc = blockIdx.y;
  const int t = threadIdx.x;
  if (b == 0 && jc == 0 && t == 0) counters[0] = 0u;   // kF last-block gate

  __shared__ float ew[128][H];       // ew[i][h] = E[h, L-1-(base+i)]   (4 KB)
  __shared__ float part[16][H][S];   // [r][h][s]                      (64 KB)
  __shared__ float tot[512];         // scan scratch                    (2 KB)

  const int base = jc * 128;
  const int dhi = L - 1 - base;
#pragma unroll
  for (int k = 0; k < 2; ++k) {
    const int idx = t + k * 512;     // [0,1024): i = idx>>3, h = idx&7
    const int i = idx >> 3, h = idx & 7;
    ew[i][h] = expf(W[(size_t)(dhi - i) * H + h]);
  }

  // --- full prefix scan for one h (8 blocks only) ---
  if (b == 0 && jc < H) {
    const int h = jc;
    const int d0 = t * 4;
    float e[4];
    float run = 0.f;
#pragma unroll
    for (int k = 0; k < 4; ++k) {
      float v = expf(W[(size_t)(d0 + k) * H + h]);
      e[k] = v; run += v;
    }
    tot[t] = run;
    __syncthreads();
    for (int off = 1; off < 512; off <<= 1) {
      float v = (t >= off) ? tot[t - off] : 0.f;
      __syncthreads();
      tot[t] += v;
      __syncthreads();
    }
    float c = (t == 0) ? 0.f : tot[t - 1];
#pragma unroll
    for (int k = 0; k < 4; ++k) {
      c += e[k];
      E[h * L + d0 + k] = e[k];
      Z[h * L + d0 + k] = c;
    }
  }
  __syncthreads();   // ew ready (and scan done)

  // --- partial_q main loop: 16 row-groups x 8 rows each ---
  const int s4 = t & 31;
  const int r = t >> 5;              // 0..15
  const float4* __restrict__ x4 = (const float4*)(x + (size_t)b * L * S);
  float4 acc[H];
#pragma unroll
  for (int h = 0; h < H; ++h) acc[h] = make_float4(0.f, 0.f, 0.f, 0.f);
#pragma unroll
  for (int k = 0; k < 8; ++k) {
    const int ll = k * 16 + r;
    const int l = base + ll;
    const float4 xv = x4[(size_t)l * 32 + s4];
#pragma unroll
    for (int h = 0; h < H; ++h) {
      const float w = ew[ll][h];
      acc[h].x += w * xv.x; acc[h].y += w * xv.y;
      acc[h].z += w * xv.z; acc[h].w += w * xv.w;
    }
  }
#pragma unroll
  for (int h = 0; h < H; ++h) {
    part[r][h][s4 * 4 + 0] = acc[h].x;
    part[r][h][s4 * 4 + 1] = acc[h].y;
    part[r][h][s4 * 4 + 2] = acc[h].z;
    part[r][h][s4 * 4 + 3] = acc[h].w;
  }
  __syncthreads();
#pragma unroll
  for (int k = 0; k < 2; ++k) {
    const int idx = t + k * 512;           // h*S + s
    const int h = idx >> 7, s = idx & 127;
    float sm = 0.f;
#pragma unroll
    for (int rr = 0; rr < 16; ++rr) sm += part[rr][h][s];
    partial_q[((size_t)b * 16 + jc) * HS + idx] = sm;
  }
}

// ============ KB: all-batch GEMV over one A-chunk ============
// grid (8 ec, 16 dc) = 128 blocks x 512 threads. e in [ec*128,+128), d in [dc*64,+64).
__global__ __launch_bounds__(512) void kB_v(const float* __restrict__ partial_q,
                                            const float* __restrict__ Z,
                                            const float* __restrict__ A,
                                            float* __restrict__ partial_v) {
  const int ebase = blockIdx.x * 128;
  const int dc = blockIdx.y;
  const int dbase = dc * 64;
  const int t = threadIdx.x;
  __shared__ float ql[8][64];          // 2 KB
  __shared__ float p2[4][8][128];      // 16 KB
  const float invZ = 1.f / Z[(dc >> 1) * L + (L - 1)];   // h = dbase>>7 = dc>>1
  {
    const int bb = t >> 6, dl = t & 63;    // 512 = 8 b x 64 d
    const float* __restrict__ pq = partial_q + ((size_t)bb * 16) * HS + dbase + dl;
    float a0 = 0.f, a1 = 0.f, a2 = 0.f, a3 = 0.f;
#pragma unroll
    for (int j4 = 0; j4 < 16; j4 += 4) {
      a0 += pq[(size_t)(j4 + 0) * HS];
      a1 += pq[(size_t)(j4 + 1) * HS];
      a2 += pq[(size_t)(j4 + 2) * HS];
      a3 += pq[(size_t)(j4 + 3) * HS];
    }
    ql[bb][dl] = ((a0 + a1) + (a2 + a3)) * invZ;
  }
  __syncthreads();
  const int el = t & 127, dg = t >> 7;     // 4 d-groups of 16
  const int e = ebase + el;
  const float* __restrict__ Ab = A + (size_t)(dbase + dg * 16) * HS + e;
  float acc[8] = {0.f, 0.f, 0.f, 0.f, 0.f, 0.f, 0.f, 0.f};
#pragma unroll 4
  for (int dd = 0; dd < 16; ++dd) {
    const float a = Ab[(size_t)dd * HS];
    const int d = dg * 16 + dd;
    acc[0] += ql[0][d] * a;
    acc[1] += ql[1][d] * a;
    acc[2] += ql[2][d] * a;
    acc[3] += ql[3][d] * a;
    acc[4] += ql[4][d] * a;
    acc[5] += ql[5][d] * a;
    acc[6] += ql[6][d] * a;
    acc[7] += ql[7][d] * a;
  }
#pragma unroll
  for (int bb = 0; bb < 8; ++bb) p2[dg][bb][el] = acc[bb];
  __syncthreads();
#pragma unroll
  for (int k = 0; k < 2; ++k) {
    const int idx = t + k * 512;        // [0,1024): bb = idx>>7, el2 = idx&127
    const int bb = idx >> 7, el2 = idx & 127;
    partial_v[((size_t)bb * 16 + dc) * HS + ebase + el2] =
        (p2[0][bb][el2] + p2[1][bb][el2]) + (p2[2][bb][el2] + p2[3][bb][el2]);
  }
}

// ============ KC: fused v-reduce + u ============
// grid (B, 16) = 128 blocks x 512 threads. j-chunks of 128. jl = t&127, sq = t>>7 (4 s-quarters).
__global__ __launch_bounds__(512) void kC_u(const float* __restrict__ x,
                                            const float* __restrict__ partial_v,
                                            float* __restrict__ u_pad) {
  const int b = blockIdx.x, jc = blockIdx.y;
  const int t = threadIdx.x;
  __shared__ float vs[HS];             // 4 KB
  __shared__ float up[4][H][128];      // 16 KB
#pragma unroll
  for (int k = 0; k < 2; ++k) {
    const int i = t + k * 512;
    float a0 = 0.f, a1 = 0.f, a2 = 0.f, a3 = 0.f;
#pragma unroll
    for (int dcc = 0; dcc < 16; dcc += 4) {
      a0 += partial_v[((size_t)b * 16 + dcc + 0) * HS + i];
      a1 += partial_v[((size_t)b * 16 + dcc + 1) * HS + i];
      a2 += partial_v[((size_t)b * 16 + dcc + 2) * HS + i];
      a3 += partial_v[((size_t)b * 16 + dcc + 3) * HS + i];
    }
    vs[i] = (a0 + a1) + (a2 + a3);
  }
  __syncthreads();
  const int jl = t & 127, sq = t >> 7;
  const int j = jc * 128 + jl;
  const float4* __restrict__ xr = (const float4*)(x + ((size_t)b * L + j) * S) + sq * 8;
  float4 xv[8];
#pragma unroll
  for (int i = 0; i < 8; ++i) xv[i] = xr[i];
  float acc[H];
#pragma unroll
  for (int h = 0; h < H; ++h) {
    const float4* __restrict__ vv = (const float4*)(vs + h * S + sq * 32);
    float a = 0.f;
#pragma unroll
    for (int i = 0; i < 8; ++i) {
      const float4 w = vv[i];   // same addr across 128-lane group -> LDS broadcast
      a += xv[i].x * w.x + xv[i].y * w.y + xv[i].z * w.z + xv[i].w * w.w;
    }
    acc[h] = a;
  }
#pragma unroll
  for (int h = 0; h < H; ++h) up[sq][h][jl] = acc[h];
  __syncthreads();
#pragma unroll
  for (int k = 0; k < 2; ++k) {
    const int idx = t + k * 512;       // [0,1024): h = idx>>7, j2 = idx&127
    const int h = idx >> 7, j2 = idx & 127;
    const float sv = (up[0][h][j2] + up[1][h][j2]) + (up[2][h][j2] + up[3][h][j2]);
    const size_t rowbase = (size_t)(b * H + h) * (2 * L);
    u_pad[rowbase + jc * 128 + j2] = 0.f;        // zero pad (front half)
    u_pad[rowbase + L + jc * 128 + j2] = sv;
  }
}

// ============ KD: conv partials, 256-wide d-tiles split in 2 halves, B*72 = 576 blocks =========
// 512 threads: tsub = t&31 (4 l each), h = (t>>5)&7, dh = t>>8 (d-half of 128).
__global__ __launch_bounds__(512) void kD_conv(const float* __restrict__ u_pad,
                                               const float* __restrict__ E,
                                               const float* __restrict__ Z,
                                               float* __restrict__ partial_s) {
  const int job = blockIdx.x;
  const int b = job / 72;
  const int rr = job - b * 72;
  int lt = 0, c = 0;
  while (c + (lt / 2 + 1) <= rr) { c += lt / 2 + 1; ++lt; }
  const int dtt = rr - c;
  const int l0 = lt * 128;
  const int t = threadIdx.x;
  const int tsub = t & 31;
  const int h = (t >> 5) & 7;
  const int dh = t >> 8;
  const int dbase = dtt * 256 + dh * 128;
  const int Lb = l0 + tsub * 4;
  const float* __restrict__ ur = u_pad + (size_t)(b * H + h) * (2 * L) + L;
  const float4* __restrict__ Eh4 = (const float4*)(E + h * L);
  float acc0 = 0.f, acc1 = 0.f, acc2 = 0.f, acc3 = 0.f;
  float4 lo = *(const float4*)(ur + Lb - dbase - 4);   // may land in zero pad: contributes 0
  float4 hi = *(const float4*)(ur + Lb - dbase);
#pragma unroll 4
  for (int dd = 0; dd < 128; dd += 4) {
    const int d0 = dbase + dd;
    float4 ev  = Eh4[d0 >> 2];                        // wave-uniform -> scalar load
    float4 nlo = *(const float4*)(ur + Lb - d0 - 8);  // zero-pad covers all
    acc0 += ev.x * hi.x; acc1 += ev.x * hi.y; acc2 += ev.x * hi.z; acc3 += ev.x * hi.w;
    acc0 += ev.y * lo.w; acc1 += ev.y * hi.x; acc2 += ev.y * hi.y; acc3 += ev.y * hi.z;
    acc0 += ev.z * lo.z; acc1 += ev.z * lo.w; acc2 += ev.z * hi.x; acc3 += ev.z * hi.y;
    acc0 += ev.w * lo.y; acc1 += ev.w * lo.z; acc2 += ev.w * lo.w; acc3 += ev.w * hi.x;
    hi = lo; lo = nlo;
  }
  __shared__ float sred[2][H][128];   // 8 KB
  const float4 zv = *(const float4*)&Z[h * L + Lb];
  sred[dh][h][tsub * 4 + 0] = acc0 / zv.x;
  sred[dh][h][tsub * 4 + 1] = acc1 / zv.y;
  sred[dh][h][tsub * 4 + 2] = acc2 / zv.z;
  sred[dh][h][tsub * 4 + 3] = acc3 / zv.w;
  __syncthreads();
  if (t < 128) {
    float sc = 0.f;
#pragma unroll
    for (int hh = 0; hh < H; ++hh) sc += sred[0][hh][t] + sred[1][hh][t];
    partial_s[((size_t)b * 8 + dtt) * L + l0 + t] = sc;
  }
}

// ============ KF: redundant softmax + 128-l weighted-sum chunk + last-block reduce ============
// grid (B, 16) = 128 blocks x 512 threads.
__global__ __launch_bounds__(512) void kF_out(const float* __restrict__ x,
                                              const float* __restrict__ partial_s,
                                              float* __restrict__ partial,
                                              unsigned* __restrict__ counters,
                                              float* __restrict__ out) {
  const int b = blockIdx.x, c = blockIdx.y;
  const int t = threadIdx.x;
  __shared__ float ep[L];          // 8 KB
  __shared__ float red[512];       // 2 KB
  __shared__ float part[16][S];    // 8 KB

  // --- Phase A: scores -> softmax weights (thread t owns l in [4t, 4t+4)) ---
  const int l0 = t * 4;
  const int ltq = t >> 6;                // (4t)>>8 = floor(lt/2)
  float sc[4] = {0.f, 0.f, 0.f, 0.f};
  for (int dtt = 0; dtt <= ltq; ++dtt) {
    const float4 a = *(const float4*)(partial_s + ((size_t)b * 8 + dtt) * L + l0);
    sc[0] += a.x; sc[1] += a.y; sc[2] += a.z; sc[3] += a.w;
  }
  if (t == 511) sc[3] = -3.4e38f;        // l = 2047 excluded
  float mx = fmaxf(fmaxf(sc[0], sc[1]), fmaxf(sc[2], sc[3]));
  red[t] = mx;
  __syncthreads();
  for (int off = 256; off > 0; off >>= 1) {
    if (t < off) red[t] = fmaxf(red[t], red[t + off]);
    __syncthreads();
  }
  mx = red[0];
  __syncthreads();
  float e[4];
  float sm = 0.f;
#pragma unroll
  for (int k = 0; k < 4; ++k) {
    e[k] = (l0 + k < L - 1) ? expf(sc[k] - mx) : 0.f;
    sm += e[k];
  }
  red[t] = sm;
  __syncthreads();
  for (int off = 256; off > 0; off >>= 1) {
    if (t < off) red[t] += red[t + off];
    __syncthreads();
  }
  const float inv = 1.f / red[0];
#pragma unroll
  for (int k = 0; k < 4; ++k) ep[l0 + k] = e[k] * inv;
  __syncthreads();

  // --- Phase B: partial[b,c,s] = sum_{l in 128-chunk c} ep[l] * x[b,l,s] ---
  const int s4 = t & 31;
  const int r = t >> 5;                  // 16 row-groups of 8 l
  const int base = c * 128;
  const float4* __restrict__ x4 = (const float4*)(x + (size_t)b * L * S);
  float4 acc = make_float4(0.f, 0.f, 0.f, 0.f);
#pragma unroll
  for (int k = 0; k < 8; ++k) {
    const int l = base + k * 16 + r;
    const float w = ep[l];
    const float4 xv = x4[(size_t)l * 32 + s4];
    acc.x += w * xv.x; acc.y += w * xv.y; acc.z += w * xv.z; acc.w += w * xv.w;
  }
  part[r][s4 * 4 + 0] = acc.x;
  part[r][s4 * 4 + 1] = acc.y;
  part[r][s4 * 4 + 2] = acc.z;
  part[r][s4 * 4 + 3] = acc.w;
  __syncthreads();
  if (t < S) {
    float smv = 0.f;
#pragma unroll
    for (int rr = 0; rr < 16; ++rr) smv += part[rr][t];
    partial[((size_t)b * 16 + c) * S + t] = smv;
  }
  // --- last-block gate (one-shot, 128 blocks) ---
  __threadfence();
  __syncthreads();
  __shared__ unsigned lastFlag;
  if (t == 0)
    lastFlag = (atomicAdd(&counters[0], 1u) == (unsigned)(B * 16 - 1)) ? 1u : 0u;
  __syncthreads();
  if (lastFlag) {
#pragma unroll
    for (int k = 0; k < 2; ++k) {
      const int idx = t + k * 512;          // b2 = idx>>7, s = idx&127
      const int b2 = idx >> 7, s = idx & 127;
      float a = 0.f;
#pragma unroll 4
      for (int cc = 0; cc < 16; ++cc) a += partial[((size_t)b2 * 16 + cc) * S + s];
      out[b2 * S + s] = a;
    }
  }
}

extern "C" void kernel_launch(void* const* d_in, const int* in_sizes, int n_in,
                              void* d_out, int out_size, void* d_ws, size_t ws_size,
                              hipStream_t stream) {
  const float* x = (const float*)d_in[0];   // (B, L, S) f32
  const float* W = (const float*)d_in[1];   // (L, H)   f32
  const float* A = (const float*)d_in[2];   // (HS, HS) f32
  float* out = (float*)d_out;               // (B, S)   f32

  float* ws        = (float*)d_ws;
  float* E         = ws;                               // H*L     = 16384
  float* Z         = E + H * L;                        // 16384
  float* partial_q = Z + H * L;                        // B*16*HS = 131072
  float* partial_v = partial_q + (size_t)B * 16 * HS;  // B*16*HS = 131072
  float* u_pad     = partial_v + (size_t)B * 16 * HS;  // B*H*2L  = 262144
  float* partial_s = u_pad + (size_t)B * H * 2 * L;    // B*8*L   = 131072
  float* partial   = partial_s + (size_t)B * 8 * L;    // B*16*S  = 16384
  unsigned* counters = (unsigned*)(partial + (size_t)B * 16 * S);
  // total ≈ 2.8 MB of d_ws

  kA_prep_qpart<<<dim3(B, 16), 512, 0, stream>>>(W, x, E, Z, partial_q, counters);
  kB_v         <<<dim3(8, 16), 512, 0, stream>>>(partial_q, Z, A, partial_v);
  kC_u         <<<dim3(B, 16), 512, 0, stream>>>(x, partial_v, u_pad);
  kD_conv      <<<B * 72,      512, 0, stream>>>(u_pad, E, Z, partial_s);
  kF_out       <<<dim3(B, 16), 512, 0, stream>>>(x, partial_s, partial, counters, out);
}

// Round 13
// 55.927 us; speedup vs baseline: 1.5052x; 1.0515x over previous
//
#include <hip/hip_runtime.h>

#define L 2048
#define H 8
#define S 128
#define B 8
#define HS 1024

// ============ KA: fused {per-b E,Z prefix-scan} + partial_q ============
// grid (B, 16) = 128 blocks x 512 threads. j-chunks of 128. Linear block id % 8 == b -> XCD b.
// Blocks (b, jc<8) write THIS b's replica of E/Z (XCD-local for kD/kF).
__global__ __launch_bounds__(512) void kA_prep_qpart(const float* __restrict__ W,
                                                     const float* __restrict__ x,
                                                     float* __restrict__ Eb,
                                                     float* __restrict__ Zb,
                                                     float* __restrict__ partial_q,
                                                     unsigned* __restrict__ counters) {
  const int b = blockIdx.x, jc = blockIdx.y;
  const int t = threadIdx.x;
  if (b == 0 && jc == 0 && t == 0) counters[0] = 0u;   // kF last-block gate

  __shared__ float ew[128][H];       // ew[i][h] = E[h, L-1-(base+i)]   (4 KB)
  __shared__ float part[16][H][S];   // [r][h][s]                      (64 KB)
  __shared__ float tot[512];         // scan scratch                    (2 KB)

  const int base = jc * 128;
  const int dhi = L - 1 - base;
#pragma unroll
  for (int k = 0; k < 2; ++k) {
    const int idx = t + k * 512;     // [0,1024): i = idx>>3, h = idx&7
    const int i = idx >> 3, h = idx & 7;
    ew[i][h] = expf(W[(size_t)(dhi - i) * H + h]);
  }

  // --- per-b full prefix scan for one h (8 blocks per b) ---
  if (jc < H) {
    const int h = jc;
    const int d0 = t * 4;
    float e[4];
    float run = 0.f;
#pragma unroll
    for (int k = 0; k < 4; ++k) {
      float v = expf(W[(size_t)(d0 + k) * H + h]);
      e[k] = v; run += v;
    }
    tot[t] = run;
    __syncthreads();
    for (int off = 1; off < 512; off <<= 1) {
      float v = (t >= off) ? tot[t - off] : 0.f;
      __syncthreads();
      tot[t] += v;
      __syncthreads();
    }
    float c = (t == 0) ? 0.f : tot[t - 1];
    const size_t ebase = (size_t)(b * H + h) * L;
#pragma unroll
    for (int k = 0; k < 4; ++k) {
      c += e[k];
      Eb[ebase + d0 + k] = e[k];
      Zb[ebase + d0 + k] = c;
    }
  }
  __syncthreads();   // ew ready (and scan done)

  // --- partial_q main loop: 16 row-groups x 8 rows each ---
  const int s4 = t & 31;
  const int r = t >> 5;              // 0..15
  const float4* __restrict__ x4 = (const float4*)(x + (size_t)b * L * S);
  float4 acc[H];
#pragma unroll
  for (int h = 0; h < H; ++h) acc[h] = make_float4(0.f, 0.f, 0.f, 0.f);
#pragma unroll
  for (int k = 0; k < 8; ++k) {
    const int ll = k * 16 + r;
    const int l = base + ll;
    const float4 xv = x4[(size_t)l * 32 + s4];
#pragma unroll
    for (int h = 0; h < H; ++h) {
      const float w = ew[ll][h];
      acc[h].x += w * xv.x; acc[h].y += w * xv.y;
      acc[h].z += w * xv.z; acc[h].w += w * xv.w;
    }
  }
#pragma unroll
  for (int h = 0; h < H; ++h) {
    part[r][h][s4 * 4 + 0] = acc[h].x;
    part[r][h][s4 * 4 + 1] = acc[h].y;
    part[r][h][s4 * 4 + 2] = acc[h].z;
    part[r][h][s4 * 4 + 3] = acc[h].w;
  }
  __syncthreads();
#pragma unroll
  for (int k = 0; k < 2; ++k) {
    const int idx = t + k * 512;           // h*S + s
    const int h = idx >> 7, s = idx & 127;
    float sm = 0.f;
#pragma unroll
    for (int rr = 0; rr < 16; ++rr) sm += part[rr][h][s];
    partial_q[((size_t)b * 16 + jc) * HS + idx] = sm;
  }
}

// ============ KB: all-batch GEMV over one A-chunk ============
// grid (8 ec, 16 dc) = 128 blocks x 512 threads. e in [ec*128,+128), d in [dc*64,+64).
__global__ __launch_bounds__(512) void kB_v(const float* __restrict__ partial_q,
                                            const float* __restrict__ Zb,
                                            const float* __restrict__ A,
                                            float* __restrict__ partial_v) {
  const int ebase = blockIdx.x * 128;
  const int dc = blockIdx.y;
  const int dbase = dc * 64;
  const int t = threadIdx.x;
  __shared__ float ql[8][64];          // 2 KB
  __shared__ float p2[4][8][128];      // 16 KB
  const float invZ = 1.f / Zb[(size_t)(dc >> 1) * L + (L - 1)];   // b=0 copy; h = dc>>1
  {
    const int bb = t >> 6, dl = t & 63;    // 512 = 8 b x 64 d
    const float* __restrict__ pq = partial_q + ((size_t)bb * 16) * HS + dbase + dl;
    float a0 = 0.f, a1 = 0.f, a2 = 0.f, a3 = 0.f;
#pragma unroll
    for (int j4 = 0; j4 < 16; j4 += 4) {
      a0 += pq[(size_t)(j4 + 0) * HS];
      a1 += pq[(size_t)(j4 + 1) * HS];
      a2 += pq[(size_t)(j4 + 2) * HS];
      a3 += pq[(size_t)(j4 + 3) * HS];
    }
    ql[bb][dl] = ((a0 + a1) + (a2 + a3)) * invZ;
  }
  __syncthreads();
  const int el = t & 127, dg = t >> 7;     // 4 d-groups of 16
  const int e = ebase + el;
  const float* __restrict__ Ab = A + (size_t)(dbase + dg * 16) * HS + e;
  float acc[8] = {0.f, 0.f, 0.f, 0.f, 0.f, 0.f, 0.f, 0.f};
#pragma unroll 4
  for (int dd = 0; dd < 16; ++dd) {
    const float a = Ab[(size_t)dd * HS];
    const int d = dg * 16 + dd;
    acc[0] += ql[0][d] * a;
    acc[1] += ql[1][d] * a;
    acc[2] += ql[2][d] * a;
    acc[3] += ql[3][d] * a;
    acc[4] += ql[4][d] * a;
    acc[5] += ql[5][d] * a;
    acc[6] += ql[6][d] * a;
    acc[7] += ql[7][d] * a;
  }
#pragma unroll
  for (int bb = 0; bb < 8; ++bb) p2[dg][bb][el] = acc[bb];
  __syncthreads();
#pragma unroll
  for (int k = 0; k < 2; ++k) {
    const int idx = t + k * 512;        // [0,1024): bb = idx>>7, el2 = idx&127
    const int bb = idx >> 7, el2 = idx & 127;
    partial_v[((size_t)bb * 16 + dc) * HS + ebase + el2] =
        (p2[0][bb][el2] + p2[1][bb][el2]) + (p2[2][bb][el2] + p2[3][bb][el2]);
  }
}

// ============ KC: fused v-reduce + u ============
// grid (B, 16) = 128 blocks x 512 threads -> XCD b. j-chunks of 128.
__global__ __launch_bounds__(512) void kC_u(const float* __restrict__ x,
                                            const float* __restrict__ partial_v,
                                            float* __restrict__ u_pad) {
  const int b = blockIdx.x, jc = blockIdx.y;
  const int t = threadIdx.x;
  __shared__ float vs[HS];             // 4 KB
  __shared__ float up[4][H][128];      // 16 KB
#pragma unroll
  for (int k = 0; k < 2; ++k) {
    const int i = t + k * 512;
    float a0 = 0.f, a1 = 0.f, a2 = 0.f, a3 = 0.f;
#pragma unroll
    for (int dcc = 0; dcc < 16; dcc += 4) {
      a0 += partial_v[((size_t)b * 16 + dcc + 0) * HS + i];
      a1 += partial_v[((size_t)b * 16 + dcc + 1) * HS + i];
      a2 += partial_v[((size_t)b * 16 + dcc + 2) * HS + i];
      a3 += partial_v[((size_t)b * 16 + dcc + 3) * HS + i];
    }
    vs[i] = (a0 + a1) + (a2 + a3);
  }
  __syncthreads();
  const int jl = t & 127, sq = t >> 7;
  const int j = jc * 128 + jl;
  const float4* __restrict__ xr = (const float4*)(x + ((size_t)b * L + j) * S) + sq * 8;
  float4 xv[8];
#pragma unroll
  for (int i = 0; i < 8; ++i) xv[i] = xr[i];
  float acc[H];
#pragma unroll
  for (int h = 0; h < H; ++h) {
    const float4* __restrict__ vv = (const float4*)(vs + h * S + sq * 32);
    float a = 0.f;
#pragma unroll
    for (int i = 0; i < 8; ++i) {
      const float4 w = vv[i];   // same addr across 128-lane group -> LDS broadcast
      a += xv[i].x * w.x + xv[i].y * w.y + xv[i].z * w.z + xv[i].w * w.w;
    }
    acc[h] = a;
  }
#pragma unroll
  for (int h = 0; h < H; ++h) up[sq][h][jl] = acc[h];
  __syncthreads();
#pragma unroll
  for (int k = 0; k < 2; ++k) {
    const int idx = t + k * 512;       // [0,1024): h = idx>>7, j2 = idx&127
    const int h = idx >> 7, j2 = idx & 127;
    const float sv = (up[0][h][j2] + up[1][h][j2]) + (up[2][h][j2] + up[3][h][j2]);
    const size_t rowbase = (size_t)(b * H + h) * (2 * L);
    u_pad[rowbase + jc * 128 + j2] = 0.f;        // zero pad (front half)
    u_pad[rowbase + L + jc * 128 + j2] = sv;
  }
}

// ============ KD: conv partials, 256-wide d-tiles split in 2 halves ============
// grid (B, 72) = 576 blocks x 512 threads -> batch b pinned to XCD b (u_pad/partial_s local).
// 512 threads: tsub = t&31 (4 l each), h = (t>>5)&7, dh = t>>8 (d-half of 128).
__global__ __launch_bounds__(512) void kD_conv(const float* __restrict__ u_pad,
                                               const float* __restrict__ Eb,
                                               const float* __restrict__ Zb,
                                               float* __restrict__ partial_s) {
  const int b = blockIdx.x;
  const int rr = blockIdx.y;
  int lt = 0, c = 0;
  while (c + (lt / 2 + 1) <= rr) { c += lt / 2 + 1; ++lt; }
  const int dtt = rr - c;
  const int l0 = lt * 128;
  const int t = threadIdx.x;
  const int tsub = t & 31;
  const int h = (t >> 5) & 7;
  const int dh = t >> 8;
  const int dbase = dtt * 256 + dh * 128;
  const int Lb = l0 + tsub * 4;
  const float* __restrict__ ur = u_pad + (size_t)(b * H + h) * (2 * L) + L;
  const float4* __restrict__ Eh4 = (const float4*)(Eb + (size_t)(b * H + h) * L);
  float acc0 = 0.f, acc1 = 0.f, acc2 = 0.f, acc3 = 0.f;
  float4 lo = *(const float4*)(ur + Lb - dbase - 4);   // may land in zero pad: contributes 0
  float4 hi = *(const float4*)(ur + Lb - dbase);
#pragma unroll 4
  for (int dd = 0; dd < 128; dd += 4) {
    const int d0 = dbase + dd;
    float4 ev  = Eh4[d0 >> 2];                        // wave-uniform -> scalar load
    float4 nlo = *(const float4*)(ur + Lb - d0 - 8);  // zero-pad covers all
    acc0 += ev.x * hi.x; acc1 += ev.x * hi.y; acc2 += ev.x * hi.z; acc3 += ev.x * hi.w;
    acc0 += ev.y * lo.w; acc1 += ev.y * hi.x; acc2 += ev.y * hi.y; acc3 += ev.y * hi.z;
    acc0 += ev.z * lo.z; acc1 += ev.z * lo.w; acc2 += ev.z * hi.x; acc3 += ev.z * hi.y;
    acc0 += ev.w * lo.y; acc1 += ev.w * lo.z; acc2 += ev.w * lo.w; acc3 += ev.w * hi.x;
    hi = lo; lo = nlo;
  }
  __shared__ float sred[2][H][128];   // 8 KB
  const float4 zv = *(const float4*)&Zb[(size_t)(b * H + h) * L + Lb];
  sred[dh][h][tsub * 4 + 0] = acc0 / zv.x;
  sred[dh][h][tsub * 4 + 1] = acc1 / zv.y;
  sred[dh][h][tsub * 4 + 2] = acc2 / zv.z;
  sred[dh][h][tsub * 4 + 3] = acc3 / zv.w;
  __syncthreads();
  if (t < 128) {
    float sc = 0.f;
#pragma unroll
    for (int hh = 0; hh < H; ++hh) sc += sred[0][hh][t] + sred[1][hh][t];
    partial_s[((size_t)b * 8 + dtt) * L + l0 + t] = sc;
  }
}

// ============ KF: redundant softmax + 128-l weighted-sum chunk + last-block reduce ============
// grid (B, 16) = 128 blocks x 512 threads -> XCD b.
__global__ __launch_bounds__(512) void kF_out(const float* __restrict__ x,
                                              const float* __restrict__ partial_s,
                                              float* __restrict__ partial,
                                              unsigned* __restrict__ counters,
                                              float* __restrict__ out) {
  const int b = blockIdx.x, c = blockIdx.y;
  const int t = threadIdx.x;
  __shared__ float ep[L];          // 8 KB
  __shared__ float red[512];       // 2 KB
  __shared__ float part[16][S];    // 8 KB

  // --- Phase A: scores -> softmax weights (thread t owns l in [4t, 4t+4)) ---
  const int l0 = t * 4;
  const int ltq = t >> 6;                // (4t)>>8 = floor(lt/2)
  float sc[4] = {0.f, 0.f, 0.f, 0.f};
  for (int dtt = 0; dtt <= ltq; ++dtt) {
    const float4 a = *(const float4*)(partial_s + ((size_t)b * 8 + dtt) * L + l0);
    sc[0] += a.x; sc[1] += a.y; sc[2] += a.z; sc[3] += a.w;
  }
  if (t == 511) sc[3] = -3.4e38f;        // l = 2047 excluded
  float mx = fmaxf(fmaxf(sc[0], sc[1]), fmaxf(sc[2], sc[3]));
  red[t] = mx;
  __syncthreads();
  for (int off = 256; off > 0; off >>= 1) {
    if (t < off) red[t] = fmaxf(red[t], red[t + off]);
    __syncthreads();
  }
  mx = red[0];
  __syncthreads();
  float e[4];
  float sm = 0.f;
#pragma unroll
  for (int k = 0; k < 4; ++k) {
    e[k] = (l0 + k < L - 1) ? expf(sc[k] - mx) : 0.f;
    sm += e[k];
  }
  red[t] = sm;
  __syncthreads();
  for (int off = 256; off > 0; off >>= 1) {
    if (t < off) red[t] += red[t + off];
    __syncthreads();
  }
  const float inv = 1.f / red[0];
#pragma unroll
  for (int k = 0; k < 4; ++k) ep[l0 + k] = e[k] * inv;
  __syncthreads();

  // --- Phase B: partial[b,c,s] = sum_{l in 128-chunk c} ep[l] * x[b,l,s] ---
  const int s4 = t & 31;
  const int r = t >> 5;                  // 16 row-groups of 8 l
  const int base = c * 128;
  const float4* __restrict__ x4 = (const float4*)(x + (size_t)b * L * S);
  float4 acc = make_float4(0.f, 0.f, 0.f, 0.f);
#pragma unroll
  for (int k = 0; k < 8; ++k) {
    const int l = base + k * 16 + r;
    const float w = ep[l];
    const float4 xv = x4[(size_t)l * 32 + s4];
    acc.x += w * xv.x; acc.y += w * xv.y; acc.z += w * xv.z; acc.w += w * xv.w;
  }
  part[r][s4 * 4 + 0] = acc.x;
  part[r][s4 * 4 + 1] = acc.y;
  part[r][s4 * 4 + 2] = acc.z;
  part[r][s4 * 4 + 3] = acc.w;
  __syncthreads();
  if (t < S) {
    float smv = 0.f;
#pragma unroll
    for (int rr = 0; rr < 16; ++rr) smv += part[rr][t];
    partial[((size_t)b * 16 + c) * S + t] = smv;
  }
  // --- last-block gate (one-shot, 128 blocks) ---
  __threadfence();
  __syncthreads();
  __shared__ unsigned lastFlag;
  if (t == 0)
    lastFlag = (atomicAdd(&counters[0], 1u) == (unsigned)(B * 16 - 1)) ? 1u : 0u;
  __syncthreads();
  if (lastFlag) {
#pragma unroll
    for (int k = 0; k < 2; ++k) {
      const int idx = t + k * 512;          // b2 = idx>>7, s = idx&127
      const int b2 = idx >> 7, s = idx & 127;
      float a = 0.f;
#pragma unroll 4
      for (int cc = 0; cc < 16; ++cc) a += partial[((size_t)b2 * 16 + cc) * S + s];
      out[b2 * S + s] = a;
    }
  }
}

extern "C" void kernel_launch(void* const* d_in, const int* in_sizes, int n_in,
                              void* d_out, int out_size, void* d_ws, size_t ws_size,
                              hipStream_t stream) {
  const float* x = (const float*)d_in[0];   // (B, L, S) f32
  const float* W = (const float*)d_in[1];   // (L, H)   f32
  const float* A = (const float*)d_in[2];   // (HS, HS) f32
  float* out = (float*)d_out;               // (B, S)   f32

  float* ws        = (float*)d_ws;
  float* Eb        = ws;                               // B*H*L   = 131072
  float* Zb        = Eb + (size_t)B * H * L;           // B*H*L   = 131072
  float* partial_q = Zb + (size_t)B * H * L;           // B*16*HS = 131072
  float* partial_v = partial_q + (size_t)B * 16 * HS;  // B*16*HS = 131072
  float* u_pad     = partial_v + (size_t)B * 16 * HS;  // B*H*2L  = 262144
  float* partial_s = u_pad + (size_t)B * H * 2 * L;    // B*8*L   = 131072
  float* partial   = partial_s + (size_t)B * 8 * L;    // B*16*S  = 16384
  unsigned* counters = (unsigned*)(partial + (size_t)B * 16 * S);
  // total ≈ 3.7 MB of d_ws

  kA_prep_qpart<<<dim3(B, 16), 512, 0, stream>>>(W, x, Eb, Zb, partial_q, counters);
  kB_v         <<<dim3(8, 16), 512, 0, stream>>>(partial_q, Zb, A, partial_v);
  kC_u         <<<dim3(B, 16), 512, 0, stream>>>(x, partial_v, u_pad);
  kD_conv      <<<dim3(B, 72), 512, 0, stream>>>(u_pad, Eb, Zb, partial_s);
  kF_out       <<<dim3(B, 16), 512, 0, stream>>>(x, partial_s, partial, counters, out);
}